// Round 3
// baseline (239.900 us; speedup 1.0000x reference)
//
#include <hip/hip_runtime.h>
#include <hip/hip_bf16.h>

// y[i, d] = x[i, d] * A_diag[d] + B[d]
// N = 262144 rows, D = 512 fp32. HBM-bound streaming FMA.
//
// Each thread owns a FIXED float4-column j = tid & 127: A/B live in 8
// registers for the whole kernel (no LDS). 4x row unroll gives 4
// independent load->fma->store chains per thread. Nontemporal hints on
// the x/out streams (each byte touched exactly once).
//
// NOTE: __builtin_nontemporal_* requires a native clang vector type, not
// HIP_vector_type<float,4> — hence the ext_vector_type alias.

typedef float f32x4 __attribute__((ext_vector_type(4)));

#define D4      128         // 512 / 4 float4 columns
#define NROWS   262144

__global__ __launch_bounds__(256) void diag_affine_kernel(
    const f32x4* __restrict__ x,
    const f32x4* __restrict__ A4,
    const f32x4* __restrict__ B4,
    f32x4* __restrict__ out)
{
    const int j = threadIdx.x & (D4 - 1);
    const f32x4 a = A4[j];
    const f32x4 b = B4[j];

    const int rows_per_step = gridDim.x * 2;                   // 4096 @ grid=2048
    int row = blockIdx.x * 2 + (threadIdx.x >> 7);

    // 262144 / (4096*4) = 16 exact iterations at grid=2048.
    for (; row + 3 * rows_per_step < NROWS; row += 4 * rows_per_step) {
        const long i0 = (long)(row)                     * D4 + j;
        const long i1 = (long)(row +     rows_per_step) * D4 + j;
        const long i2 = (long)(row + 2 * rows_per_step) * D4 + j;
        const long i3 = (long)(row + 3 * rows_per_step) * D4 + j;

        f32x4 v0 = __builtin_nontemporal_load(&x[i0]);
        f32x4 v1 = __builtin_nontemporal_load(&x[i1]);
        f32x4 v2 = __builtin_nontemporal_load(&x[i2]);
        f32x4 v3 = __builtin_nontemporal_load(&x[i3]);

        f32x4 r0 = v0 * a + b;
        f32x4 r1 = v1 * a + b;
        f32x4 r2 = v2 * a + b;
        f32x4 r3 = v3 * a + b;

        __builtin_nontemporal_store(r0, &out[i0]);
        __builtin_nontemporal_store(r1, &out[i1]);
        __builtin_nontemporal_store(r2, &out[i2]);
        __builtin_nontemporal_store(r3, &out[i3]);
    }
    // tail (not taken at grid=2048, kept for safety)
    for (; row < NROWS; row += rows_per_step) {
        const long i = (long)row * D4 + j;
        f32x4 v = __builtin_nontemporal_load(&x[i]);
        f32x4 r = v * a + b;
        __builtin_nontemporal_store(r, &out[i]);
    }
}

extern "C" void kernel_launch(void* const* d_in, const int* in_sizes, int n_in,
                              void* d_out, int out_size, void* d_ws, size_t ws_size,
                              hipStream_t stream) {
    const float* x = (const float*)d_in[0];
    const float* A = (const float*)d_in[1];
    const float* B = (const float*)d_in[2];
    float* out = (float*)d_out;

    const int block = 256;
    const int grid = 2048;   // 8 blocks/CU x 256 CUs

    diag_affine_kernel<<<grid, block, 0, stream>>>(
        reinterpret_cast<const f32x4*>(x),
        reinterpret_cast<const f32x4*>(A),
        reinterpret_cast<const f32x4*>(B),
        reinterpret_cast<f32x4*>(out));
}

// Round 4
// 194.454 us; speedup vs baseline: 1.2337x; 1.2337x over previous
//
#include <hip/hip_runtime.h>
#include <hip/hip_bf16.h>

// y[i, d] = x[i, d] * A_diag[d] + B[d]
// N = 262144 rows, D = 512 fp32. HBM-bound streaming FMA.
//
// R4 structure: no LDS (a/b register-held, loaded once from the 2KB A/B
// arrays which stay in L2/L3), contiguous-chunk 4x unroll (each block
// iteration covers one contiguous 16KB chunk: 4 wave-segments at
// +0/+4/+8/+12 KB -> 4 independent load->fma->store chains with intact
// DRAM locality). Normal cached loads/stores (R3's nontemporal hints
// regressed 226->240us).

typedef float f32x4 __attribute__((ext_vector_type(4)));

#define D4 128                          // 512 / 4 float4 columns
constexpr long N4 = 262144L * D4;       // 33,554,432 float4 elements

__global__ __launch_bounds__(256) void diag_affine_kernel(
    const f32x4* __restrict__ x,
    const f32x4* __restrict__ A4,
    const f32x4* __restrict__ B4,
    f32x4* __restrict__ out)
{
    // Column is loop-invariant: chunk bases are multiples of 1024 and the
    // intra-chunk offsets are multiples of 256, so (index & 127) == tid & 127.
    const int j = threadIdx.x & (D4 - 1);
    const f32x4 a = A4[j];
    const f32x4 b = B4[j];

    const long chunk = 1024;                              // float4s per block-iter
    const long step  = (long)gridDim.x * chunk;           // 2,097,152 @ grid=2048

    for (long base = (long)blockIdx.x * chunk + threadIdx.x; base < N4; base += step) {
        f32x4 v0 = x[base];
        f32x4 v1 = x[base + 256];
        f32x4 v2 = x[base + 512];
        f32x4 v3 = x[base + 768];

        out[base]       = v0 * a + b;
        out[base + 256] = v1 * a + b;
        out[base + 512] = v2 * a + b;
        out[base + 768] = v3 * a + b;
    }
}

extern "C" void kernel_launch(void* const* d_in, const int* in_sizes, int n_in,
                              void* d_out, int out_size, void* d_ws, size_t ws_size,
                              hipStream_t stream) {
    const float* x = (const float*)d_in[0];
    const float* A = (const float*)d_in[1];
    const float* B = (const float*)d_in[2];
    float* out = (float*)d_out;

    const int block = 256;
    const int grid = 2048;   // 16 exact iterations of 16KB chunks per block

    diag_affine_kernel<<<grid, block, 0, stream>>>(
        reinterpret_cast<const f32x4*>(x),
        reinterpret_cast<const f32x4*>(A),
        reinterpret_cast<const f32x4*>(B),
        reinterpret_cast<f32x4*>(out));
}